// Round 15
// baseline (564.456 us; speedup 1.0000x reference)
//
#include <hip/hip_runtime.h>
#include <stdint.h>

// ---------------------------------------------------------------------------
// SPP: out[n] = b + W @ [mean0(b) | mean2(s2) | mean4(s4) | mean8(s8)]
// v15: = v14 with k_scatter2 re-laid-out: 8 points/wave, 8 lanes/point,
//      16B/lane (2x dwordx4 NT loads, solo = 1 dwordx4 store, multi = 4
//      pk-atomics). Halves load instrs, quarters solo-store instrs; same
//      atomic count. Everything else v14 verbatim (386.5us best).
// ---------------------------------------------------------------------------

#define N_PTS   1048576
#define NB      4
#define N2SEG   (NB*64*64*64)   // 1,048,576
#define N4SEG   (NB*32*32*32)   // 131,072
#define N8SEG   (NB*16*16*16)   // 16,384

typedef unsigned int uint;

// workspace offsets (bytes)
#define OFF_SUMS2  ((size_t)0)            // N2SEG*64 bf16 = 134,217,728 (mean2, NOT pre-zeroed)
#define OFF_CNT2   ((size_t)134217728)    // N2SEG u32     =   4,194,304 (zeroed)
#define OFF_SUMS0F ((size_t)138412032)    // 256 f32 (pad 1024, zeroed; contiguous w/ cnt2)
#define ZERO_BEG   OFF_CNT2
#define ZERO_END   ((size_t)138413056)
#define OFF_SUMS4  ((size_t)138413056)    // N4SEG*64 bf16 =  16,777,216 (raw sums)
#define OFF_MEAN4  ((size_t)155190272)    // N4SEG*64 bf16 =  16,777,216
#define OFF_CNT4   ((size_t)171967488)    // N4SEG u32     =     524,288
#define OFF_SUMS8  ((size_t)172491776)    // N8SEG*64 bf16 =   2,097,152 (raw sums)
#define OFF_MEAN8  ((size_t)174588928)    // N8SEG*64 bf16 =   2,097,152
#define OFF_CNT8   ((size_t)176686080)    // N8SEG u32     =      65,536
#define OFF_WF     ((size_t)176752640)    // 48 KB frag-ready W
#define OFF_BIAS0  ((size_t)176801792)    // 4*96 f32 (pad 2048)
#define OFF_S2ARR  ((size_t)176803840)    // N_PTS u32 = 4,194,304
#define WS_NEEDED  ((size_t)180998144)

// dword offsets into workspace (for k_final's single-base addressing)
#define D_S2 0u
#define D_M4 ((uint)(OFF_MEAN4 / 4))
#define D_M8 ((uint)(OFF_MEAN8 / 4))

typedef short s8v __attribute__((ext_vector_type(8)));   // 8 bf16 (4 VGPR)
typedef float f4v __attribute__((ext_vector_type(4)));   // MFMA C/D
typedef uint  u4v __attribute__((ext_vector_type(4)));
typedef float f4l __attribute__((ext_vector_type(4)));   // NT f32x4 load

__device__ __forceinline__ uint pack_bf16x2(float a, float b) {
  uint ua = __float_as_uint(a), ub = __float_as_uint(b);
  ua = (ua + 0x7fffu + ((ua >> 16) & 1u)) >> 16;   // RNE
  ub = (ub + 0x7fffu + ((ub >> 16) & 1u)) >> 16;
  return (ub << 16) | ua;
}
__device__ __forceinline__ float bflo(uint u) { return __uint_as_float(u << 16); }
__device__ __forceinline__ float bfhi(uint u) { return __uint_as_float(u & 0xffff0000u); }

// ---- zero cnt2 + sums0f (contiguous, 4,195,328 B)
#define ZCNT_U4 ((ZERO_END - ZERO_BEG) / 16)
__global__ __launch_bounds__(256) void k_zero_cnt(u4v* __restrict__ p) {
  u4v z = (u4v)0u;
  size_t stride = (size_t)gridDim.x * 256;
  for (size_t i = blockIdx.x * 256ull + threadIdx.x; i < ZCNT_U4; i += stride)
    __builtin_nontemporal_store(z, &p[i]);
}

// ---- phase 1: count points per level-2 voxel; also materialize s2arr[p]
__global__ __launch_bounds__(256) void k_cnt(
    const int* __restrict__ coords, const int* __restrict__ batch,
    uint* __restrict__ cnt2, uint* __restrict__ s2arr)
{
  int p = blockIdx.x * 256 + threadIdx.x;          // grid sized exactly N_PTS
  int b = batch[p];
  int x = coords[3 * p], y = coords[3 * p + 1], z = coords[3 * p + 2];
  uint s2 = (uint)(((b * 64 + (x >> 1)) * 64 + (y >> 1)) * 64 + (z >> 1));
  s2arr[p] = s2;
  atomicAdd(&cnt2[s2], 1u);
}

// ---- phase 1.5: zero only rows that will be atomically accumulated (cnt>=2)
__global__ __launch_bounds__(256) void k_zmulti(
    const uint* __restrict__ cnt2, u4v* __restrict__ sums2q)
{
  int tid = blockIdx.x * 256 + threadIdx.x;        // grid = N2SEG*8 exactly
  int seg = tid >> 3, part = tid & 7;
  if (cnt2[seg] >= 2u) sums2q[seg * 8 + part] = (u4v)0u;
}

// ---- frag-ready W: Wf[((kt*6+nt)*64+l)*4+d] = pack(W[n][k], W[n][k+1])
//      n = nt*16+(l&15), k = kt*32+(l>>4)*8+2d   (B[k][n] = W[n][k])
__global__ __launch_bounds__(256) void k_wf(const float* __restrict__ W,
                                            uint* __restrict__ Wf) {
  int idx = blockIdx.x * 256 + threadIdx.x;        // < 12288
  int d = idx & 3, l = (idx >> 2) & 63, ktnt = idx >> 8;
  int kt = ktnt / 6, nt = ktnt - kt * 6;
  int n = nt * 16 + (l & 15);
  int k = kt * 32 + (l >> 4) * 8 + d * 2;
  Wf[idx] = pack_bf16x2(W[n * 256 + k], W[n * 256 + k + 1]);
}

// ---- phase 2: scatter PRE-SCALED feats (f/cnt). 8 points/wave, 8 lanes/pt,
//      16B/lane. cnt==1 -> dwordx4 store (rc==1, bit-identical);
//      cnt>=2 -> 4x pk-bf16 atomic into zeroed row.
__global__ __launch_bounds__(256) void k_scatter2(
    const float* __restrict__ feats, const uint* __restrict__ s2arr,
    uint* __restrict__ sums2, const uint* __restrict__ cnt2)
{
  int l = threadIdx.x & 63;
  int pt = l >> 3, ch8 = l & 7;                    // point-in-group, 8-ch chunk
  int wid = (blockIdx.x * 256 + threadIdx.x) >> 6;
  int nw = (gridDim.x * 256) >> 6;
  #pragma unroll 1
  for (int g0 = wid * 8; g0 < N_PTS; g0 += nw * 8) {
    int p = g0 + pt;
    uint s2 = s2arr[p];                            // 8 lanes same addr: broadcast
    uint cv = cnt2[s2];
    const f4l* fp = (const f4l*)(feats + (size_t)p * 64 + ch8 * 8);
    f4l fa = __builtin_nontemporal_load(fp);
    f4l fb = __builtin_nontemporal_load(fp + 1);
    float rc = 1.0f / (float)cv;                   // cv >= 1 always
    uint4 pk;
    pk.x = pack_bf16x2(fa.x * rc, fa.y * rc);
    pk.y = pack_bf16x2(fa.z * rc, fa.w * rc);
    pk.z = pack_bf16x2(fb.x * rc, fb.y * rc);
    pk.w = pack_bf16x2(fb.z * rc, fb.w * rc);
    uint* dst = sums2 + (size_t)s2 * 32 + ch8 * 4;
    if (cv == 1u) {
      *(uint4*)dst = pk;                           // solo voxel: exact
    } else {
      uint64_t a0 = (uint64_t)(uintptr_t)(dst + 0);
      uint64_t a1 = (uint64_t)(uintptr_t)(dst + 1);
      uint64_t a2 = (uint64_t)(uintptr_t)(dst + 2);
      uint64_t a3 = (uint64_t)(uintptr_t)(dst + 3);
      asm volatile("global_atomic_pk_add_bf16 %0, %1, off" :: "v"(a0), "v"(pk.x));
      asm volatile("global_atomic_pk_add_bf16 %0, %1, off" :: "v"(a1), "v"(pk.y));
      asm volatile("global_atomic_pk_add_bf16 %0, %1, off" :: "v"(a2), "v"(pk.z));
      asm volatile("global_atomic_pk_add_bf16 %0, %1, off" :: "v"(a3), "v"(pk.w));
    }
  }
}

// ---- 8-child tree reduction; cnt-guarded. fromMean: child buffer holds
//      means -> reconstruct sums as mean*cnt. Writes raw sums, pre-scaled
//      mean, and cnt.
__global__ __launch_bounds__(256) void k_down_bf(
    const uint* __restrict__ sumsF, const uint* __restrict__ cntF,
    uint* __restrict__ sumsC, uint* __restrict__ meanC,
    uint* __restrict__ cntC, int lgC, int nC, int fromMean)
{
  int tid = blockIdx.x * 256 + threadIdx.x;
  int sc = tid >> 5, c2 = tid & 31;
  if (sc >= nC) return;
  int CG = 1 << lgC, FG = CG << 1;
  int b = sc >> (3 * lgC);
  int r = sc & ((1 << (3 * lgC)) - 1);
  int x = r >> (2 * lgC), y = (r >> lgC) & (CG - 1), z = r & (CG - 1);
  float sx = 0.f, sy = 0.f;
  uint cn = 0;
  #pragma unroll
  for (int dx = 0; dx < 2; ++dx)
    #pragma unroll
    for (int dy = 0; dy < 2; ++dy)
      #pragma unroll
      for (int dz = 0; dz < 2; ++dz) {
        int sf = ((b * FG + 2 * x + dx) * FG + (2 * y + dy)) * FG + (2 * z + dz);
        uint cf = cntF[sf];               // same addr across 32 lanes: broadcast
        if (cf) {
          uint u = sumsF[(size_t)sf * 32 + c2];
          float wgt = fromMean ? (float)cf : 1.0f;
          sx += bflo(u) * wgt; sy += bfhi(u) * wgt;
        }
        cn += cf;
      }
  sumsC[(size_t)sc * 32 + c2] = pack_bf16x2(sx, sy);
  float rc = 1.0f / (float)(cn > 1u ? cn : 1u);
  meanC[(size_t)sc * 32 + c2] = pack_bf16x2(sx * rc, sy * rc);
  if (c2 == 0) cntC[sc] = cn;
}

// ---- per-batch global partial reduce (32 blocks/batch), f32 atomics
__global__ __launch_bounds__(256) void k_gpart(
    const uint* __restrict__ sums8, float* __restrict__ sums0f)
{
  __shared__ float2 red[8][32];
  int b = blockIdx.x >> 5, chunk = blockIdx.x & 31;
  int t = threadIdx.x, c2 = t & 31, g = t >> 5;
  float sx = 0.f, sy = 0.f;
  for (int i = g; i < 128; i += 8) {
    uint u = sums8[(size_t)(b * 4096 + chunk * 128 + i) * 32 + c2];
    sx += bflo(u); sy += bfhi(u);
  }
  red[g][c2] = make_float2(sx, sy);
  __syncthreads();
  if (g == 0) {
    float ax = 0.f, ay = 0.f;
    #pragma unroll
    for (int i = 0; i < 8; ++i) { ax += red[i][c2].x; ay += red[i][c2].y; }
    unsafeAtomicAdd(&sums0f[b * 64 + 2 * c2], ax);
    unsafeAtomicAdd(&sums0f[b * 64 + 2 * c2 + 1], ay);
  }
}

// ---- finalize level 0: cnt0 from cnt8; bias0[b][o] = bias[o] + W0 @ mean0[b]
__global__ __launch_bounds__(256) void k_fin0(
    const float* __restrict__ sums0f, const uint* __restrict__ cnt8,
    const float* __restrict__ W, const float* __restrict__ bias,
    float* __restrict__ bias0)
{
  __shared__ uint redc[256];
  __shared__ float rcs[NB];
  __shared__ float m0[NB * 64];
  int t = threadIdx.x;
  uint cn = 0;
  for (int i = 0; i < 64; ++i) cn += cnt8[t * 64 + i];
  redc[t] = cn;
  __syncthreads();
  if (t < NB) {
    uint s = 0;
    for (int i = 0; i < 64; ++i) s += redc[t * 64 + i];
    rcs[t] = 1.0f / (float)(s > 1u ? s : 1u);
  }
  __syncthreads();
  if (t < NB * 64) m0[t] = sums0f[t] * rcs[t >> 6];
  __syncthreads();
  for (int i = t; i < NB * 96; i += 256) {
    int b = i / 96, o = i - b * 96;
    float s = bias[o];
    const float* wr = W + (size_t)o * 256;
    #pragma unroll 8
    for (int k = 0; k < 64; ++k) s += wr[k] * m0[b * 64 + k];
    bias0[i] = s;
  }
}

// ---- fused gather-GEMM (v14 exact): all levels pre-scaled -> no cnt gather,
//      no scale VALU. 6-frag payload, s2-only LDS idx, bias0 table; depth-3
//      pipeline; 39.5KB LDS -> 4 blocks/CU.
#define GPB 8

#define ISSUE(G, AF) {                                                       \
    uint s2i = idx_lds[(G) * 64 + w16pl];                                    \
    uint bb = s2i >> 18, X = (s2i >> 12) & 63u, Y = (s2i >> 6) & 63u,        \
         Z = s2i & 63u;                                                      \
    uint s4i = ((bb * 32 + (X >> 1)) * 32 + (Y >> 1)) * 32 + (Z >> 1);       \
    uint s8i = ((bb * 16 + (X >> 2)) * 16 + (Y >> 2)) * 16 + (Z >> 2);       \
    const uint4* a2 = (const uint4*)(wsb + D_S2 + s2i * 32u);                \
    const uint4* a4 = (const uint4*)(wsb + D_M4 + s4i * 32u);                \
    const uint4* a8 = (const uint4*)(wsb + D_M8 + s8i * 32u);                \
    AF[0] = a2[q];  AF[1] = a2[4 + q];                                       \
    AF[2] = a4[q];  AF[3] = a4[4 + q];                                       \
    AF[4] = a8[q];  AF[5] = a8[4 + q];                                       \
  }

#define CONSUME(G, AF) {                                                     \
    f4v acc[6];                                                              \
    _Pragma("unroll")                                                        \
    for (int nt = 0; nt < 6; ++nt) acc[nt] = (f4v)0.0f;                      \
    _Pragma("unroll")                                                        \
    for (int kt = 0; kt < 6; ++kt) {                                         \
      s8v afr = __builtin_bit_cast(s8v, AF[kt]);                             \
      _Pragma("unroll")                                                      \
      for (int nt = 0; nt < 6; ++nt) {                                       \
        s8v bf = __builtin_bit_cast(s8v, wf[(kt * 6 + nt) * 64 + l]);        \
        acc[nt] = __builtin_amdgcn_mfma_f32_16x16x32_bf16(afr, bf, acc[nt], 0, 0, 0); \
      }                                                                      \
    }                                                                        \
    int base = (G) * 64 + w * 16 + q * 4;                                    \
    float* ob = out + (size_t)(pb + base) * 96 + pl;                         \
    _Pragma("unroll")                                                        \
    for (int r = 0; r < 4; ++r) {                                            \
      uint br = idx_lds[base + r] >> 18;                                     \
      const float* bp = &bias0_l[br * 96 + pl];                              \
      _Pragma("unroll")                                                      \
      for (int nt = 0; nt < 6; ++nt)                                         \
        ob[r * 96 + nt * 16] = bp[nt * 16] + acc[nt][r];                     \
    }                                                                        \
  }

__global__ __launch_bounds__(256) void k_final(
    const uint* __restrict__ s2arr,
    const uint* __restrict__ wsb,     // workspace base, dword-indexed
    const uint4* __restrict__ Wf, const float* __restrict__ bias0,
    float* __restrict__ out)
{
  __shared__ uint4 wf[2304];      // 36 KB: W tiles for kt=2..7 (levels 2/4/8)
  __shared__ uint idx_lds[512];   // 2 KB: s2 per point (s4/s8/b derived)
  __shared__ float bias0_l[NB * 96];  // 1.5 KB
  int t = threadIdx.x;
  #pragma unroll
  for (int i = 0; i < 9; ++i) wf[i * 256 + t] = Wf[768 + i * 256 + t];
  #pragma unroll
  for (int j = 0; j < 2; ++j) {
    int i = t + j * 256;
    if (i < NB * 96) bias0_l[i] = bias0[i];
  }
  int pb = blockIdx.x * (GPB * 64);
  #pragma unroll
  for (int j = 0; j < 2; ++j) {
    int pi = t + j * 256;
    idx_lds[pi] = s2arr[pb + pi];
  }
  int l = t & 63, w = t >> 6, pl = l & 15, q = l >> 4;
  int w16pl = w * 16 + pl;
  __syncthreads();

  uint4 b0[6], b1[6], b2[6];
  ISSUE(0, b0)
  ISSUE(1, b1)
  ISSUE(2, b2)  CONSUME(0, b0)
  ISSUE(3, b0)  CONSUME(1, b1)
  ISSUE(4, b1)  CONSUME(2, b2)
  ISSUE(5, b2)  CONSUME(3, b0)
  ISSUE(6, b0)  CONSUME(4, b1)
  ISSUE(7, b1)  CONSUME(5, b2)
  CONSUME(6, b0)
  CONSUME(7, b1)
}

extern "C" void kernel_launch(void* const* d_in, const int* in_sizes, int n_in,
                              void* d_out, int out_size, void* d_ws, size_t ws_size,
                              hipStream_t stream)
{
  const float* feats  = (const float*)d_in[0];
  const int*   coords = (const int*)d_in[1];
  const int*   batch  = (const int*)d_in[2];
  const float* W      = (const float*)d_in[3];
  const float* bias   = (const float*)d_in[4];
  float* out = (float*)d_out;
  char* ws = (char*)d_ws;
  if (ws_size < WS_NEEDED) return;

  uint*  sums2  = (uint*)(ws + OFF_SUMS2);
  uint*  cnt2   = (uint*)(ws + OFF_CNT2);
  float* sums0f = (float*)(ws + OFF_SUMS0F);
  uint*  sums4  = (uint*)(ws + OFF_SUMS4);
  uint*  mean4  = (uint*)(ws + OFF_MEAN4);
  uint*  cnt4   = (uint*)(ws + OFF_CNT4);
  uint*  sums8  = (uint*)(ws + OFF_SUMS8);
  uint*  mean8  = (uint*)(ws + OFF_MEAN8);
  uint*  cnt8   = (uint*)(ws + OFF_CNT8);
  uint*  Wf     = (uint*)(ws + OFF_WF);
  float* bias0  = (float*)(ws + OFF_BIAS0);
  uint*  s2arr  = (uint*)(ws + OFF_S2ARR);

  k_wf<<<48, 256, 0, stream>>>(W, Wf);
  k_zero_cnt<<<1024, 256, 0, stream>>>((u4v*)(ws + ZERO_BEG));
  k_cnt<<<N_PTS / 256, 256, 0, stream>>>(coords, batch, cnt2, s2arr);
  k_zmulti<<<(N2SEG * 8) / 256, 256, 0, stream>>>(cnt2, (u4v*)sums2);
  k_scatter2<<<8192, 256, 0, stream>>>(feats, s2arr, sums2, cnt2);
  k_down_bf<<<(N4SEG * 32) / 256, 256, 0, stream>>>(sums2, cnt2, sums4, mean4, cnt4, 5, N4SEG, 1);
  k_down_bf<<<(N8SEG * 32) / 256, 256, 0, stream>>>(sums4, cnt4, sums8, mean8, cnt8, 4, N8SEG, 0);
  k_gpart<<<128, 256, 0, stream>>>(sums8, sums0f);
  k_fin0<<<1, 256, 0, stream>>>(sums0f, cnt8, W, bias, bias0);
  k_final<<<N_PTS / (GPB * 64), 256, 0, stream>>>(
      s2arr, (const uint*)ws, (const uint4*)Wf, bias0, out);
}

// Round 16
// 384.125 us; speedup vs baseline: 1.4695x; 1.4695x over previous
//
#include <hip/hip_runtime.h>
#include <stdint.h>

// ---------------------------------------------------------------------------
// SPP: out[n] = b + W @ [mean0(b) | mean2(s2) | mean4(s4) | mean8(s8)]
// v16: = v14 (386.5us best) with scatter's prefetch extended to feats.
//      v15's 8-lane/point scatter regressed (VGPR 16 -> zero ILP, serial
//      dependent chain, 285us) and is reverted.
// ---------------------------------------------------------------------------

#define N_PTS   1048576
#define NB      4
#define N2SEG   (NB*64*64*64)   // 1,048,576
#define N4SEG   (NB*32*32*32)   // 131,072
#define N8SEG   (NB*16*16*16)   // 16,384

typedef unsigned int uint;

// workspace offsets (bytes)
#define OFF_SUMS2  ((size_t)0)            // N2SEG*64 bf16 = 134,217,728 (mean2, NOT pre-zeroed)
#define OFF_CNT2   ((size_t)134217728)    // N2SEG u32     =   4,194,304 (zeroed)
#define OFF_SUMS0F ((size_t)138412032)    // 256 f32 (pad 1024, zeroed; contiguous w/ cnt2)
#define ZERO_BEG   OFF_CNT2
#define ZERO_END   ((size_t)138413056)
#define OFF_SUMS4  ((size_t)138413056)    // N4SEG*64 bf16 =  16,777,216 (raw sums)
#define OFF_MEAN4  ((size_t)155190272)    // N4SEG*64 bf16 =  16,777,216
#define OFF_CNT4   ((size_t)171967488)    // N4SEG u32     =     524,288
#define OFF_SUMS8  ((size_t)172491776)    // N8SEG*64 bf16 =   2,097,152 (raw sums)
#define OFF_MEAN8  ((size_t)174588928)    // N8SEG*64 bf16 =   2,097,152
#define OFF_CNT8   ((size_t)176686080)    // N8SEG u32     =      65,536
#define OFF_WF     ((size_t)176752640)    // 48 KB frag-ready W
#define OFF_BIAS0  ((size_t)176801792)    // 4*96 f32 (pad 2048)
#define OFF_S2ARR  ((size_t)176803840)    // N_PTS u32 = 4,194,304
#define WS_NEEDED  ((size_t)180998144)

// dword offsets into workspace (for k_final's single-base addressing)
#define D_S2 0u
#define D_M4 ((uint)(OFF_MEAN4 / 4))
#define D_M8 ((uint)(OFF_MEAN8 / 4))

typedef short s8v __attribute__((ext_vector_type(8)));   // 8 bf16 (4 VGPR)
typedef float f4v __attribute__((ext_vector_type(4)));   // MFMA C/D
typedef uint  u4v __attribute__((ext_vector_type(4)));
typedef float f2v __attribute__((ext_vector_type(2)));

__device__ __forceinline__ uint pack_bf16x2(float a, float b) {
  uint ua = __float_as_uint(a), ub = __float_as_uint(b);
  ua = (ua + 0x7fffu + ((ua >> 16) & 1u)) >> 16;   // RNE
  ub = (ub + 0x7fffu + ((ub >> 16) & 1u)) >> 16;
  return (ub << 16) | ua;
}
__device__ __forceinline__ float bflo(uint u) { return __uint_as_float(u << 16); }
__device__ __forceinline__ float bfhi(uint u) { return __uint_as_float(u & 0xffff0000u); }

// ---- zero cnt2 + sums0f (contiguous, 4,195,328 B)
#define ZCNT_U4 ((ZERO_END - ZERO_BEG) / 16)
__global__ __launch_bounds__(256) void k_zero_cnt(u4v* __restrict__ p) {
  u4v z = (u4v)0u;
  size_t stride = (size_t)gridDim.x * 256;
  for (size_t i = blockIdx.x * 256ull + threadIdx.x; i < ZCNT_U4; i += stride)
    __builtin_nontemporal_store(z, &p[i]);
}

// ---- phase 1: count points per level-2 voxel; also materialize s2arr[p]
__global__ __launch_bounds__(256) void k_cnt(
    const int* __restrict__ coords, const int* __restrict__ batch,
    uint* __restrict__ cnt2, uint* __restrict__ s2arr)
{
  int p = blockIdx.x * 256 + threadIdx.x;          // grid sized exactly N_PTS
  int b = batch[p];
  int x = coords[3 * p], y = coords[3 * p + 1], z = coords[3 * p + 2];
  uint s2 = (uint)(((b * 64 + (x >> 1)) * 64 + (y >> 1)) * 64 + (z >> 1));
  s2arr[p] = s2;
  atomicAdd(&cnt2[s2], 1u);
}

// ---- phase 1.5: zero only rows that will be atomically accumulated (cnt>=2)
__global__ __launch_bounds__(256) void k_zmulti(
    const uint* __restrict__ cnt2, u4v* __restrict__ sums2q)
{
  int tid = blockIdx.x * 256 + threadIdx.x;        // grid = N2SEG*8 exactly
  int seg = tid >> 3, part = tid & 7;
  if (cnt2[seg] >= 2u) sums2q[seg * 8 + part] = (u4v)0u;
}

// ---- frag-ready W: Wf[((kt*6+nt)*64+l)*4+d] = pack(W[n][k], W[n][k+1])
//      n = nt*16+(l&15), k = kt*32+(l>>4)*8+2d   (B[k][n] = W[n][k])
__global__ __launch_bounds__(256) void k_wf(const float* __restrict__ W,
                                            uint* __restrict__ Wf) {
  int idx = blockIdx.x * 256 + threadIdx.x;        // < 12288
  int d = idx & 3, l = (idx >> 2) & 63, ktnt = idx >> 8;
  int kt = ktnt / 6, nt = ktnt - kt * 6;
  int n = nt * 16 + (l & 15);
  int k = kt * 32 + (l >> 4) * 8 + d * 2;
  Wf[idx] = pack_bf16x2(W[n * 256 + k], W[n * 256 + k + 1]);
}

// ---- phase 2: scatter PRE-SCALED feats (f/cnt), v14 layout (2 pts/wave,
//      2 ch/lane) with s2/cv AND feats prefetched one iteration ahead.
//      cnt==1 -> plain store (rc==1, bit-identical); cnt>=2 -> pk-atomic.
__global__ __launch_bounds__(256) void k_scatter2(
    const float* __restrict__ feats, const uint* __restrict__ s2arr,
    uint* __restrict__ sums2, const uint* __restrict__ cnt2)
{
  int l = threadIdx.x & 63;
  int c2 = l & 31, half = l >> 5;
  int wid = (blockIdx.x * 256 + threadIdx.x) >> 6;
  int step = (gridDim.x * 256) >> 5;               // nw * 2
  int p = wid * 2 + half;
  uint s2 = s2arr[p];
  uint cv = cnt2[s2];                               // broadcast (32 lanes same)
  f2v f = __builtin_nontemporal_load(((const f2v*)feats) + (size_t)p * 32 + c2);
  #pragma unroll 1
  for (int it = 0; it < N_PTS; it += step) {
    int pn = p + step;
    uint s2n = 0, cvn = 0;
    f2v fn = (f2v)0.f;
    if (pn < N_PTS) {                               // prefetch next iteration
      s2n = s2arr[pn]; cvn = cnt2[s2n];
      fn = __builtin_nontemporal_load(((const f2v*)feats) + (size_t)pn * 32 + c2);
    }
    float rc = 1.0f / (float)cv;                    // cv >= 1 always here
    uint pk = pack_bf16x2(f.x * rc, f.y * rc);
    uint* dst = sums2 + (size_t)s2 * 32 + c2;
    if (cv == 1u) {
      *dst = pk;                          // solo voxel: rc==1, exact
    } else {
      uint64_t addr = (uint64_t)(uintptr_t)dst;
      asm volatile("global_atomic_pk_add_bf16 %0, %1, off"
                   :: "v"(addr), "v"(pk));
    }
    p = pn; s2 = s2n; cv = cvn; f = fn;
  }
}

// ---- 8-child tree reduction; cnt-guarded. fromMean: child buffer holds
//      means -> reconstruct sums as mean*cnt. Writes raw sums, pre-scaled
//      mean, and cnt.
__global__ __launch_bounds__(256) void k_down_bf(
    const uint* __restrict__ sumsF, const uint* __restrict__ cntF,
    uint* __restrict__ sumsC, uint* __restrict__ meanC,
    uint* __restrict__ cntC, int lgC, int nC, int fromMean)
{
  int tid = blockIdx.x * 256 + threadIdx.x;
  int sc = tid >> 5, c2 = tid & 31;
  if (sc >= nC) return;
  int CG = 1 << lgC, FG = CG << 1;
  int b = sc >> (3 * lgC);
  int r = sc & ((1 << (3 * lgC)) - 1);
  int x = r >> (2 * lgC), y = (r >> lgC) & (CG - 1), z = r & (CG - 1);
  float sx = 0.f, sy = 0.f;
  uint cn = 0;
  #pragma unroll
  for (int dx = 0; dx < 2; ++dx)
    #pragma unroll
    for (int dy = 0; dy < 2; ++dy)
      #pragma unroll
      for (int dz = 0; dz < 2; ++dz) {
        int sf = ((b * FG + 2 * x + dx) * FG + (2 * y + dy)) * FG + (2 * z + dz);
        uint cf = cntF[sf];               // same addr across 32 lanes: broadcast
        if (cf) {
          uint u = sumsF[(size_t)sf * 32 + c2];
          float wgt = fromMean ? (float)cf : 1.0f;
          sx += bflo(u) * wgt; sy += bfhi(u) * wgt;
        }
        cn += cf;
      }
  sumsC[(size_t)sc * 32 + c2] = pack_bf16x2(sx, sy);
  float rc = 1.0f / (float)(cn > 1u ? cn : 1u);
  meanC[(size_t)sc * 32 + c2] = pack_bf16x2(sx * rc, sy * rc);
  if (c2 == 0) cntC[sc] = cn;
}

// ---- per-batch global partial reduce (32 blocks/batch), f32 atomics
__global__ __launch_bounds__(256) void k_gpart(
    const uint* __restrict__ sums8, float* __restrict__ sums0f)
{
  __shared__ float2 red[8][32];
  int b = blockIdx.x >> 5, chunk = blockIdx.x & 31;
  int t = threadIdx.x, c2 = t & 31, g = t >> 5;
  float sx = 0.f, sy = 0.f;
  for (int i = g; i < 128; i += 8) {
    uint u = sums8[(size_t)(b * 4096 + chunk * 128 + i) * 32 + c2];
    sx += bflo(u); sy += bfhi(u);
  }
  red[g][c2] = make_float2(sx, sy);
  __syncthreads();
  if (g == 0) {
    float ax = 0.f, ay = 0.f;
    #pragma unroll
    for (int i = 0; i < 8; ++i) { ax += red[i][c2].x; ay += red[i][c2].y; }
    unsafeAtomicAdd(&sums0f[b * 64 + 2 * c2], ax);
    unsafeAtomicAdd(&sums0f[b * 64 + 2 * c2 + 1], ay);
  }
}

// ---- finalize level 0: cnt0 from cnt8; bias0[b][o] = bias[o] + W0 @ mean0[b]
__global__ __launch_bounds__(256) void k_fin0(
    const float* __restrict__ sums0f, const uint* __restrict__ cnt8,
    const float* __restrict__ W, const float* __restrict__ bias,
    float* __restrict__ bias0)
{
  __shared__ uint redc[256];
  __shared__ float rcs[NB];
  __shared__ float m0[NB * 64];
  int t = threadIdx.x;
  uint cn = 0;
  for (int i = 0; i < 64; ++i) cn += cnt8[t * 64 + i];
  redc[t] = cn;
  __syncthreads();
  if (t < NB) {
    uint s = 0;
    for (int i = 0; i < 64; ++i) s += redc[t * 64 + i];
    rcs[t] = 1.0f / (float)(s > 1u ? s : 1u);
  }
  __syncthreads();
  if (t < NB * 64) m0[t] = sums0f[t] * rcs[t >> 6];
  __syncthreads();
  for (int i = t; i < NB * 96; i += 256) {
    int b = i / 96, o = i - b * 96;
    float s = bias[o];
    const float* wr = W + (size_t)o * 256;
    #pragma unroll 8
    for (int k = 0; k < 64; ++k) s += wr[k] * m0[b * 64 + k];
    bias0[i] = s;
  }
}

// ---- fused gather-GEMM (v14 exact): all levels pre-scaled -> no cnt gather,
//      no scale VALU. 6-frag payload, s2-only LDS idx, bias0 table; depth-3
//      pipeline; 39.5KB LDS -> 4 blocks/CU.
#define GPB 8

#define ISSUE(G, AF) {                                                       \
    uint s2i = idx_lds[(G) * 64 + w16pl];                                    \
    uint bb = s2i >> 18, X = (s2i >> 12) & 63u, Y = (s2i >> 6) & 63u,        \
         Z = s2i & 63u;                                                      \
    uint s4i = ((bb * 32 + (X >> 1)) * 32 + (Y >> 1)) * 32 + (Z >> 1);       \
    uint s8i = ((bb * 16 + (X >> 2)) * 16 + (Y >> 2)) * 16 + (Z >> 2);       \
    const uint4* a2 = (const uint4*)(wsb + D_S2 + s2i * 32u);                \
    const uint4* a4 = (const uint4*)(wsb + D_M4 + s4i * 32u);                \
    const uint4* a8 = (const uint4*)(wsb + D_M8 + s8i * 32u);                \
    AF[0] = a2[q];  AF[1] = a2[4 + q];                                       \
    AF[2] = a4[q];  AF[3] = a4[4 + q];                                       \
    AF[4] = a8[q];  AF[5] = a8[4 + q];                                       \
  }

#define CONSUME(G, AF) {                                                     \
    f4v acc[6];                                                              \
    _Pragma("unroll")                                                        \
    for (int nt = 0; nt < 6; ++nt) acc[nt] = (f4v)0.0f;                      \
    _Pragma("unroll")                                                        \
    for (int kt = 0; kt < 6; ++kt) {                                         \
      s8v afr = __builtin_bit_cast(s8v, AF[kt]);                             \
      _Pragma("unroll")                                                      \
      for (int nt = 0; nt < 6; ++nt) {                                       \
        s8v bf = __builtin_bit_cast(s8v, wf[(kt * 6 + nt) * 64 + l]);        \
        acc[nt] = __builtin_amdgcn_mfma_f32_16x16x32_bf16(afr, bf, acc[nt], 0, 0, 0); \
      }                                                                      \
    }                                                                        \
    int base = (G) * 64 + w * 16 + q * 4;                                    \
    float* ob = out + (size_t)(pb + base) * 96 + pl;                         \
    _Pragma("unroll")                                                        \
    for (int r = 0; r < 4; ++r) {                                            \
      uint br = idx_lds[base + r] >> 18;                                     \
      const float* bp = &bias0_l[br * 96 + pl];                              \
      _Pragma("unroll")                                                      \
      for (int nt = 0; nt < 6; ++nt)                                         \
        ob[r * 96 + nt * 16] = bp[nt * 16] + acc[nt][r];                     \
    }                                                                        \
  }

__global__ __launch_bounds__(256) void k_final(
    const uint* __restrict__ s2arr,
    const uint* __restrict__ wsb,     // workspace base, dword-indexed
    const uint4* __restrict__ Wf, const float* __restrict__ bias0,
    float* __restrict__ out)
{
  __shared__ uint4 wf[2304];      // 36 KB: W tiles for kt=2..7 (levels 2/4/8)
  __shared__ uint idx_lds[512];   // 2 KB: s2 per point (s4/s8/b derived)
  __shared__ float bias0_l[NB * 96];  // 1.5 KB
  int t = threadIdx.x;
  #pragma unroll
  for (int i = 0; i < 9; ++i) wf[i * 256 + t] = Wf[768 + i * 256 + t];
  #pragma unroll
  for (int j = 0; j < 2; ++j) {
    int i = t + j * 256;
    if (i < NB * 96) bias0_l[i] = bias0[i];
  }
  int pb = blockIdx.x * (GPB * 64);
  #pragma unroll
  for (int j = 0; j < 2; ++j) {
    int pi = t + j * 256;
    idx_lds[pi] = s2arr[pb + pi];
  }
  int l = t & 63, w = t >> 6, pl = l & 15, q = l >> 4;
  int w16pl = w * 16 + pl;
  __syncthreads();

  uint4 b0[6], b1[6], b2[6];
  ISSUE(0, b0)
  ISSUE(1, b1)
  ISSUE(2, b2)  CONSUME(0, b0)
  ISSUE(3, b0)  CONSUME(1, b1)
  ISSUE(4, b1)  CONSUME(2, b2)
  ISSUE(5, b2)  CONSUME(3, b0)
  ISSUE(6, b0)  CONSUME(4, b1)
  ISSUE(7, b1)  CONSUME(5, b2)
  CONSUME(6, b0)
  CONSUME(7, b1)
}

extern "C" void kernel_launch(void* const* d_in, const int* in_sizes, int n_in,
                              void* d_out, int out_size, void* d_ws, size_t ws_size,
                              hipStream_t stream)
{
  const float* feats  = (const float*)d_in[0];
  const int*   coords = (const int*)d_in[1];
  const int*   batch  = (const int*)d_in[2];
  const float* W      = (const float*)d_in[3];
  const float* bias   = (const float*)d_in[4];
  float* out = (float*)d_out;
  char* ws = (char*)d_ws;
  if (ws_size < WS_NEEDED) return;

  uint*  sums2  = (uint*)(ws + OFF_SUMS2);
  uint*  cnt2   = (uint*)(ws + OFF_CNT2);
  float* sums0f = (float*)(ws + OFF_SUMS0F);
  uint*  sums4  = (uint*)(ws + OFF_SUMS4);
  uint*  mean4  = (uint*)(ws + OFF_MEAN4);
  uint*  cnt4   = (uint*)(ws + OFF_CNT4);
  uint*  sums8  = (uint*)(ws + OFF_SUMS8);
  uint*  mean8  = (uint*)(ws + OFF_MEAN8);
  uint*  cnt8   = (uint*)(ws + OFF_CNT8);
  uint*  Wf     = (uint*)(ws + OFF_WF);
  float* bias0  = (float*)(ws + OFF_BIAS0);
  uint*  s2arr  = (uint*)(ws + OFF_S2ARR);

  k_wf<<<48, 256, 0, stream>>>(W, Wf);
  k_zero_cnt<<<1024, 256, 0, stream>>>((u4v*)(ws + ZERO_BEG));
  k_cnt<<<N_PTS / 256, 256, 0, stream>>>(coords, batch, cnt2, s2arr);
  k_zmulti<<<(N2SEG * 8) / 256, 256, 0, stream>>>(cnt2, (u4v*)sums2);
  k_scatter2<<<8192, 256, 0, stream>>>(feats, s2arr, sums2, cnt2);
  k_down_bf<<<(N4SEG * 32) / 256, 256, 0, stream>>>(sums2, cnt2, sums4, mean4, cnt4, 5, N4SEG, 1);
  k_down_bf<<<(N8SEG * 32) / 256, 256, 0, stream>>>(sums4, cnt4, sums8, mean8, cnt8, 4, N8SEG, 0);
  k_gpart<<<128, 256, 0, stream>>>(sums8, sums0f);
  k_fin0<<<1, 256, 0, stream>>>(sums0f, cnt8, W, bias, bias0);
  k_final<<<N_PTS / (GPB * 64), 256, 0, stream>>>(
      s2arr, (const uint*)ws, (const uint4*)Wf, bias0, out);
}